// Round 4
// baseline (158.767 us; speedup 1.0000x reference)
//
#include <hip/hip_runtime.h>
#include <math.h>

#define BB 4
#define NN 1024
#define HH 8
#define NROW (BB*NN)  // 4096

typedef short s8v __attribute__((ext_vector_type(8)));
typedef float f4v __attribute__((ext_vector_type(4)));

__device__ __forceinline__ float lrelu(float x) { return fmaxf(x, 0.2f * x); }
__device__ __forceinline__ short bf16rne(float f) {
    unsigned u = __float_as_uint(f);
    u += 0x7FFF + ((u >> 16) & 1u);
    return (short)(u >> 16);
}

// ---------------------------------------------------------------------------
// K1: g = h@W (8 rows/block, 512 blocks) + fused e_i/e_j via shfl-xor reduce.
// Also writes e_jt[b][h][n] (transposed copy) for k_out's per-tile staging.
// ---------------------------------------------------------------------------
__global__ __launch_bounds__(256) void k_gemm_ei(const float* __restrict__ hm,
                                                 const float* __restrict__ W,
                                                 const float* __restrict__ aw,
                                                 float* __restrict__ g,
                                                 float* __restrict__ e_i,
                                                 float* __restrict__ e_j,
                                                 float* __restrict__ e_jt) {
    __shared__ __align__(16) float hs[8][256];
    __shared__ float aws[64];
    const int row0 = blockIdx.x * 8;
    const int t = threadIdx.x;
    if (t < 64) aws[t] = aw[t];
    const float4* h4 = (const float4*)(hm + row0 * 256);
    float4* hs4 = (float4*)&hs[0][0];
    hs4[t] = h4[t];
    hs4[t + 256] = h4[t + 256];
    __syncthreads();

    float acc[8];
#pragma unroll
    for (int r = 0; r < 8; ++r) acc[r] = 0.f;
    for (int k4 = 0; k4 < 64; ++k4) {
        const float w0 = W[(4 * k4 + 0) * 256 + t];
        const float w1 = W[(4 * k4 + 1) * 256 + t];
        const float w2 = W[(4 * k4 + 2) * 256 + t];
        const float w3 = W[(4 * k4 + 3) * 256 + t];
#pragma unroll
        for (int r = 0; r < 8; ++r) {
            const float4 hv = *(const float4*)&hs[r][4 * k4];  // broadcast read
            acc[r] = fmaf(hv.x, w0, acc[r]);
            acc[r] = fmaf(hv.y, w1, acc[r]);
            acc[r] = fmaf(hv.z, w2, acc[r]);
            acc[r] = fmaf(hv.w, w3, acc[r]);
        }
    }
    const int d = t & 31, hh = t >> 5;
    const int b = row0 >> 10;
#pragma unroll
    for (int r = 0; r < 8; ++r) {
        g[(row0 + r) * 256 + t] = acc[r];
        float vi = acc[r] * aws[d];
        float vj = acc[r] * aws[32 + d];
#pragma unroll
        for (int m = 1; m < 32; m <<= 1) {
            vi += __shfl_xor(vi, m);
            vj += __shfl_xor(vj, m);
        }
        if (d == 0) {
            e_i[(row0 + r) * 8 + hh] = vi;
            e_j[(row0 + r) * 8 + hh] = vj;
            e_jt[(size_t)(b * 8 + hh) * NN + ((row0 + r) & (NN - 1))] = vj;
        }
    }
}

// ---------------------------------------------------------------------------
// K2: column-sum partials ps[ic][(b*N+j)*8+h] = sum over i-chunk of
//     adj[b,i,j]*exp(lrelu(e_i+e_j)).  512 blocks = b x 16 j-chunks x 8 i-chunks.
// ---------------------------------------------------------------------------
__global__ __launch_bounds__(256) void k_s(const float* __restrict__ adj,
                                           const float* __restrict__ e_i,
                                           const float* __restrict__ e_j,
                                           float* __restrict__ ps) {
    __shared__ __align__(16) float eis[128 * 8];
    __shared__ float ejs[8][64];
    __shared__ float sp[4][8][64];
    const int bx = blockIdx.x;
    const int b = bx >> 7, jc = (bx >> 3) & 15, ic = bx & 7;
    const int j0 = jc * 64, i0 = ic * 128;
    const int t = threadIdx.x;

    ((float4*)eis)[t] = ((const float4*)(e_i + (b * NN + i0) * 8))[t];
    if (t < 128) {
        const float4 v = ((const float4*)(e_j + (b * NN + j0) * 8))[t];
        const int base = t * 4;
        ejs[(base + 0) & 7][(base + 0) >> 3] = v.x;
        ejs[(base + 1) & 7][(base + 1) >> 3] = v.y;
        ejs[(base + 2) & 7][(base + 2) >> 3] = v.z;
        ejs[(base + 3) & 7][(base + 3) >> 3] = v.w;
    }
    __syncthreads();

    const int ii = t >> 6, jj = t & 63;
    float ejv[8], sacc[8];
#pragma unroll
    for (int h = 0; h < 8; ++h) { ejv[h] = ejs[h][jj]; sacc[h] = 0.f; }
    const float* adjp = adj + (size_t)b * NN * NN + j0 + jj;
    for (int i = ii; i < 128; i += 4) {
        const float a = adjp[(size_t)(i0 + i) * NN];
        const float* ep = &eis[i * 8];
#pragma unroll
        for (int h = 0; h < 8; ++h)
            sacc[h] = fmaf(a, __expf(lrelu(ep[h] + ejv[h])), sacc[h]);
    }
#pragma unroll
    for (int h = 0; h < 8; ++h) sp[ii][h][jj] = sacc[h];
    __syncthreads();
#pragma unroll
    for (int k = 0; k < 2; ++k) {
        const int idx = t * 2 + k;
        const int jjo = idx >> 3, h = idx & 7;
        const float s = sp[0][h][jjo] + sp[1][h][jjo] + sp[2][h][jjo] + sp[3][h][jjo];
        ps[ic * (NROW * 8) + (b * NN + j0 + jjo) * 8 + h] = s;
    }
}

// ---------------------------------------------------------------------------
// K3: rs = 1/sum(ps); Gt[b][h][jt(32)][d(32)][jj(32)] = bf16(g[j][h,d] * rs)
// ---------------------------------------------------------------------------
__global__ __launch_bounds__(256) void k_prep(const float* __restrict__ ps,
                                              const float* __restrict__ g,
                                              short* __restrict__ Gt) {
    __shared__ float rss[16][8];
    const int bx = blockIdx.x;
    const int b = bx >> 6, j0 = (bx & 63) * 16;
    const int t = threadIdx.x;
    if (t < 128) {
        const int jj = t >> 3, h = t & 7;
        float s = 0.f;
#pragma unroll
        for (int ic = 0; ic < 8; ++ic)
            s += ps[ic * (NROW * 8) + (b * NN + j0 + jj) * 8 + h];
        rss[jj][h] = 1.0f / s;
    }
    __syncthreads();
    const int h = t >> 5, d = t & 31;
    unsigned short v16[16];
#pragma unroll
    for (int r = 0; r < 16; ++r) {
        const float val = g[(size_t)(b * NN + j0 + r) * 256 + t] * rss[r][h];
        v16[r] = (unsigned short)bf16rne(val);
    }
    const int jt = j0 >> 5, jj0 = j0 & 31;
    short* dst = Gt + ((size_t)((b * 8 + h) * 32 + jt)) * 1024 + d * 32 + jj0;
    uint4 w0, w1;
    w0.x = (unsigned)v16[0] | ((unsigned)v16[1] << 16);
    w0.y = (unsigned)v16[2] | ((unsigned)v16[3] << 16);
    w0.z = (unsigned)v16[4] | ((unsigned)v16[5] << 16);
    w0.w = (unsigned)v16[6] | ((unsigned)v16[7] << 16);
    w1.x = (unsigned)v16[8] | ((unsigned)v16[9] << 16);
    w1.y = (unsigned)v16[10] | ((unsigned)v16[11] << 16);
    w1.z = (unsigned)v16[12] | ((unsigned)v16[13] << 16);
    w1.w = (unsigned)v16[14] | ((unsigned)v16[15] << 16);
    *(uint4*)dst = w0;
    *(uint4*)(dst + 8) = w1;
}

// ---------------------------------------------------------------------------
// K4: MFMA contraction. 512 blocks = (h-half, b, i-tile16); 4 waves, 1 head
// each. P generated in registers in A-frag layout (m=lane&15, k=quad*8+e).
// SPILL FIX (r4): adj/ej fragments held in f4v ext-vector arrays, constant-
// indexed only — never address-cast scalar arrays (r3 spilled 128B/thread
// per super-step to scratch -> 85MB WRITE_SIZE, 60us).
// ---------------------------------------------------------------------------
__global__ __launch_bounds__(256) void k_out_mfma(const float* __restrict__ adj,
                                                  const short* __restrict__ Gt,
                                                  const float* __restrict__ e_i,
                                                  const float* __restrict__ e_jt,
                                                  float* __restrict__ out) {
    __shared__ short gts[4][4][32][40];  // 40KB: [h-local][jt-local][d][jj+pad]
    __shared__ float ejt[4][128];        // 2KB
    const int bx = blockIdx.x;
    const int hs = bx >> 8, b = (bx >> 6) & 3, i0 = (bx & 63) * 16;
    const int t = threadIdx.x;
    const int wave = t >> 6, lane = t & 63;
    const int m = lane & 15, q = lane >> 4;
    const int h = hs * 4 + wave;  // this wave's head

    const float ei = e_i[(size_t)(b * NN + i0 + m) * 8 + h];
    f4v acc0 = {0.f, 0.f, 0.f, 0.f}, acc1 = {0.f, 0.f, 0.f, 0.f};

    const float* adjrow = adj + (size_t)b * NN * NN + (size_t)(i0 + m) * NN;
    f4v adjc[8], adjn[8];  // 8 j's per lt as two f4v; constant-indexed only
#pragma unroll
    for (int lt = 0; lt < 4; ++lt) {
        adjc[lt * 2 + 0] = *(const f4v*)&adjrow[lt * 32 + q * 8];
        adjc[lt * 2 + 1] = *(const f4v*)&adjrow[lt * 32 + q * 8 + 4];
    }
    const float4* gtg4 = (const float4*)Gt;  // 8 shorts per float4
    const float4* ejt4 = (const float4*)(e_jt + (size_t)b * 8 * NN);

    for (int s = 0; s < 8; ++s) {
        // ---- stage Gt super-tile (4h x 4jt x 32d x 32jj) + ej slice
        float4 gv[8];
#pragma unroll
        for (int p = 0; p < 8; ++p) {
            const int u = t + 256 * p;  // 16B unit: [hl(2)|jtl(2)|d(5)|c4(2)]
            gv[p] = gtg4[(size_t)(b * 8 + hs * 4 + (u >> 9)) * 4096 + s * 512 + (u & 511)];
        }
        float4 ev;
        if (t < 128) ev = ejt4[(size_t)(hs * 4 + (t >> 5)) * 256 + s * 32 + (t & 31)];
        __syncthreads();  // prior super's LDS reads done
#pragma unroll
        for (int p = 0; p < 8; ++p) {
            const int u = t + 256 * p;
            char* dst = (char*)gts + (u >> 9) * 10240 + ((u >> 7) & 3) * 2560 +
                        ((u >> 2) & 31) * 80 + (u & 3) * 16;
            *(float4*)dst = gv[p];
        }
        if (t < 128) *(float4*)&ejt[t >> 5][(t & 31) * 4] = ev;
        __syncthreads();  // LDS tile visible

        // ---- prefetch next super-step's adj into vector regs
        const int sn = (s + 1) & 7;
#pragma unroll
        for (int lt = 0; lt < 4; ++lt) {
            adjn[lt * 2 + 0] = *(const f4v*)&adjrow[sn * 128 + lt * 32 + q * 8];
            adjn[lt * 2 + 1] = *(const f4v*)&adjrow[sn * 128 + lt * 32 + q * 8 + 4];
        }

        // ---- compute: 4 j-steps of 32
#pragma unroll
        for (int lt = 0; lt < 4; ++lt) {
            const f4v ej0 = *(const f4v*)&ejt[wave][lt * 32 + q * 8];
            const f4v ej1 = *(const f4v*)&ejt[wave][lt * 32 + q * 8 + 4];
            s8v A;
#pragma unroll
            for (int e = 0; e < 4; ++e) {
                A[e]     = bf16rne(adjc[lt * 2 + 0][e] * __expf(lrelu(ei + ej0[e])));
                A[e + 4] = bf16rne(adjc[lt * 2 + 1][e] * __expf(lrelu(ei + ej1[e])));
            }
            const s8v B0 = *(const s8v*)&gts[wave][lt][m][q * 8];
            const s8v B1 = *(const s8v*)&gts[wave][lt][m + 16][q * 8];
            acc0 = __builtin_amdgcn_mfma_f32_16x16x32_bf16(A, B0, acc0, 0, 0, 0);
            acc1 = __builtin_amdgcn_mfma_f32_16x16x32_bf16(A, B1, acc1, 0, 0, 0);
        }
#pragma unroll
        for (int k = 0; k < 8; ++k) adjc[k] = adjn[k];
    }

    // ---- epilogue: C layout col=lane&15, row=quad*4+reg
    float* op = out + (size_t)(b * NN + i0) * 256;
#pragma unroll
    for (int r = 0; r < 4; ++r) {
        const int row = q * 4 + r;
        op[(size_t)row * 256 + h * 32 + m] = acc0[r];
        op[(size_t)row * 256 + h * 32 + 16 + m] = acc1[r];
    }
}

// ---------------------------------------------------------------------------
extern "C" void kernel_launch(void* const* d_in, const int* in_sizes, int n_in,
                              void* d_out, int out_size, void* d_ws, size_t ws_size,
                              hipStream_t stream) {
    const float* h      = (const float*)d_in[0];  // [4,1024,256]
    const float* adj    = (const float*)d_in[1];  // [4,1024,1024,1]
    const float* W      = (const float*)d_in[2];  // [256,256]
    const float* attn_w = (const float*)d_in[3];  // [64]
    float* out = (float*)d_out;                   // [4,1024,256]

    float* ws = (float*)d_ws;
    float* g    = ws;                    // 1,048,576 f
    float* e_i  = g + NROW * 256;        // 32,768 f
    float* e_j  = e_i + NROW * 8;        // 32,768 f
    float* e_jt = e_j + NROW * 8;        // 32,768 f  [b][h][n]
    float* ps   = e_jt + NROW * 8;       // 262,144 f
    short* Gt   = (short*)(ps + 8 * NROW * 8);  // 2,097,152 shorts (4MB)

    k_gemm_ei<<<NROW / 8, 256, 0, stream>>>(h, W, attn_w, g, e_i, e_j, e_jt);
    k_s<<<512, 256, 0, stream>>>(adj, e_i, e_j, ps);
    k_prep<<<256, 256, 0, stream>>>(ps, g, Gt);
    k_out_mfma<<<512, 256, 0, stream>>>(adj, Gt, e_i, e_jt, out);
}

// Round 5
// 123.278 us; speedup vs baseline: 1.2879x; 1.2879x over previous
//
#include <hip/hip_runtime.h>
#include <math.h>

#define BB 4
#define NN 1024
#define HH 8
#define NROW (BB*NN)  // 4096

typedef short s8v __attribute__((ext_vector_type(8)));
typedef float f4v __attribute__((ext_vector_type(4)));

__device__ __forceinline__ float lrelu(float x) { return fmaxf(x, 0.2f * x); }
__device__ __forceinline__ short bf16rne(float f) {
    unsigned u = __float_as_uint(f);
    u += 0x7FFF + ((u >> 16) & 1u);
    return (short)(u >> 16);
}

// ---------------------------------------------------------------------------
// K1: g = h@W (8 rows/block, 512 blocks) + fused e_i/e_j via shfl-xor reduce.
// Also writes e_jt[b][h][n] (transposed copy) for k_out's per-tile staging.
// ---------------------------------------------------------------------------
__global__ __launch_bounds__(256) void k_gemm_ei(const float* __restrict__ hm,
                                                 const float* __restrict__ W,
                                                 const float* __restrict__ aw,
                                                 float* __restrict__ g,
                                                 float* __restrict__ e_i,
                                                 float* __restrict__ e_j,
                                                 float* __restrict__ e_jt) {
    __shared__ __align__(16) float hs[8][256];
    __shared__ float aws[64];
    const int row0 = blockIdx.x * 8;
    const int t = threadIdx.x;
    if (t < 64) aws[t] = aw[t];
    const float4* h4 = (const float4*)(hm + row0 * 256);
    float4* hs4 = (float4*)&hs[0][0];
    hs4[t] = h4[t];
    hs4[t + 256] = h4[t + 256];
    __syncthreads();

    float acc[8];
#pragma unroll
    for (int r = 0; r < 8; ++r) acc[r] = 0.f;
    for (int k4 = 0; k4 < 64; ++k4) {
        const float w0 = W[(4 * k4 + 0) * 256 + t];
        const float w1 = W[(4 * k4 + 1) * 256 + t];
        const float w2 = W[(4 * k4 + 2) * 256 + t];
        const float w3 = W[(4 * k4 + 3) * 256 + t];
#pragma unroll
        for (int r = 0; r < 8; ++r) {
            const float4 hv = *(const float4*)&hs[r][4 * k4];  // broadcast read
            acc[r] = fmaf(hv.x, w0, acc[r]);
            acc[r] = fmaf(hv.y, w1, acc[r]);
            acc[r] = fmaf(hv.z, w2, acc[r]);
            acc[r] = fmaf(hv.w, w3, acc[r]);
        }
    }
    const int d = t & 31, hh = t >> 5;
    const int b = row0 >> 10;
#pragma unroll
    for (int r = 0; r < 8; ++r) {
        g[(row0 + r) * 256 + t] = acc[r];
        float vi = acc[r] * aws[d];
        float vj = acc[r] * aws[32 + d];
#pragma unroll
        for (int mm = 1; mm < 32; mm <<= 1) {
            vi += __shfl_xor(vi, mm);
            vj += __shfl_xor(vj, mm);
        }
        if (d == 0) {
            e_i[(row0 + r) * 8 + hh] = vi;
            e_j[(row0 + r) * 8 + hh] = vj;
            e_jt[(size_t)(b * 8 + hh) * NN + ((row0 + r) & (NN - 1))] = vj;
        }
    }
}

// ---------------------------------------------------------------------------
// K2: column-sum partials ps[ic][(b*N+j)*8+h] = sum over i-chunk of
//     adj[b,i,j]*exp(lrelu(e_i+e_j)).  512 blocks = b x 16 j-chunks x 8 i-chunks.
// ---------------------------------------------------------------------------
__global__ __launch_bounds__(256) void k_s(const float* __restrict__ adj,
                                           const float* __restrict__ e_i,
                                           const float* __restrict__ e_j,
                                           float* __restrict__ ps) {
    __shared__ __align__(16) float eis[128 * 8];
    __shared__ float ejs[8][64];
    __shared__ float sp[4][8][64];
    const int bx = blockIdx.x;
    const int b = bx >> 7, jc = (bx >> 3) & 15, ic = bx & 7;
    const int j0 = jc * 64, i0 = ic * 128;
    const int t = threadIdx.x;

    ((float4*)eis)[t] = ((const float4*)(e_i + (b * NN + i0) * 8))[t];
    if (t < 128) {
        const float4 v = ((const float4*)(e_j + (b * NN + j0) * 8))[t];
        const int base = t * 4;
        ejs[(base + 0) & 7][(base + 0) >> 3] = v.x;
        ejs[(base + 1) & 7][(base + 1) >> 3] = v.y;
        ejs[(base + 2) & 7][(base + 2) >> 3] = v.z;
        ejs[(base + 3) & 7][(base + 3) >> 3] = v.w;
    }
    __syncthreads();

    const int ii = t >> 6, jj = t & 63;
    float ejv[8], sacc[8];
#pragma unroll
    for (int h = 0; h < 8; ++h) { ejv[h] = ejs[h][jj]; sacc[h] = 0.f; }
    const float* adjp = adj + (size_t)b * NN * NN + j0 + jj;
    for (int i = ii; i < 128; i += 4) {
        const float a = adjp[(size_t)(i0 + i) * NN];
        const float* ep = &eis[i * 8];
#pragma unroll
        for (int h = 0; h < 8; ++h)
            sacc[h] = fmaf(a, __expf(lrelu(ep[h] + ejv[h])), sacc[h]);
    }
#pragma unroll
    for (int h = 0; h < 8; ++h) sp[ii][h][jj] = sacc[h];
    __syncthreads();
#pragma unroll
    for (int k = 0; k < 2; ++k) {
        const int idx = t * 2 + k;
        const int jjo = idx >> 3, h = idx & 7;
        const float s = sp[0][h][jjo] + sp[1][h][jjo] + sp[2][h][jjo] + sp[3][h][jjo];
        ps[ic * (NROW * 8) + (b * NN + j0 + jjo) * 8 + h] = s;
    }
}

// ---------------------------------------------------------------------------
// K3: rs = 1/sum(ps); Gt[b][h][jt(32)][d(32)][jj(32)] = bf16(g[j][h,d] * rs)
// ---------------------------------------------------------------------------
__global__ __launch_bounds__(256) void k_prep(const float* __restrict__ ps,
                                              const float* __restrict__ g,
                                              short* __restrict__ Gt) {
    __shared__ float rss[16][8];
    const int bx = blockIdx.x;
    const int b = bx >> 6, j0 = (bx & 63) * 16;
    const int t = threadIdx.x;
    if (t < 128) {
        const int jj = t >> 3, h = t & 7;
        float s = 0.f;
#pragma unroll
        for (int ic = 0; ic < 8; ++ic)
            s += ps[ic * (NROW * 8) + (b * NN + j0 + jj) * 8 + h];
        rss[jj][h] = 1.0f / s;
    }
    __syncthreads();
    const int h = t >> 5, d = t & 31;
    unsigned short v16[16];
#pragma unroll
    for (int r = 0; r < 16; ++r) {
        const float val = g[(size_t)(b * NN + j0 + r) * 256 + t] * rss[r][h];
        v16[r] = (unsigned short)bf16rne(val);
    }
    const int jt = j0 >> 5, jj0 = j0 & 31;
    short* dst = Gt + ((size_t)((b * 8 + h) * 32 + jt)) * 1024 + d * 32 + jj0;
    uint4 w0, w1;
    w0.x = (unsigned)v16[0] | ((unsigned)v16[1] << 16);
    w0.y = (unsigned)v16[2] | ((unsigned)v16[3] << 16);
    w0.z = (unsigned)v16[4] | ((unsigned)v16[5] << 16);
    w0.w = (unsigned)v16[6] | ((unsigned)v16[7] << 16);
    w1.x = (unsigned)v16[8] | ((unsigned)v16[9] << 16);
    w1.y = (unsigned)v16[10] | ((unsigned)v16[11] << 16);
    w1.z = (unsigned)v16[12] | ((unsigned)v16[13] << 16);
    w1.w = (unsigned)v16[14] | ((unsigned)v16[15] << 16);
    *(uint4*)dst = w0;
    *(uint4*)(dst + 8) = w1;
}

// ---------------------------------------------------------------------------
// K4: MFMA contraction. 512 blocks = (h-half, b, i-tile16); 4 waves, 1 head
// each. P generated in registers in A-frag layout (m=lane&15, k=quad*8+e).
// SCRATCH FIX (r5): ZERO local arrays in the hot loop — r3/r4 showed any
// local array here goes to scratch (85MB WRITE_SIZE, 60us). All tiles held
// in NAMED float4/f4v variables via macro expansion; no rotate loops.
// ---------------------------------------------------------------------------
__global__ __launch_bounds__(256) void k_out_mfma(const float* __restrict__ adj,
                                                  const short* __restrict__ Gt,
                                                  const float* __restrict__ e_i,
                                                  const float* __restrict__ e_jt,
                                                  float* __restrict__ out) {
    __shared__ short gts[4][4][32][40];  // 40KB: [h-local][jt-local][d][jj+pad]
    __shared__ float ejt[4][128];        // 2KB
    const int bx = blockIdx.x;
    const int hs = bx >> 8, b = (bx >> 6) & 3, i0 = (bx & 63) * 16;
    const int t = threadIdx.x;
    const int wave = t >> 6, lane = t & 63;
    const int m = lane & 15, q = lane >> 4;
    const int h = hs * 4 + wave;  // this wave's head

    const float ei = e_i[(size_t)(b * NN + i0 + m) * 8 + h];
    f4v acc0 = {0.f, 0.f, 0.f, 0.f}, acc1 = {0.f, 0.f, 0.f, 0.f};

    const float* adjrow = adj + (size_t)b * NN * NN + (size_t)(i0 + m) * NN;
    const float4* gtg4 = (const float4*)Gt;  // 8 shorts per float4
    const float4* ejt4 = (const float4*)(e_jt + (size_t)b * 8 * NN);

    for (int s = 0; s < 8; ++s) {
        // ---- issue Gt loads (named regs g0..g7) + adj loads (a0..a7) + ej
        float4 g0, g1, g2, g3, g4, g5, g6, g7;
#define LG(k)                                                                     \
        {                                                                         \
            const int u = t + 256 * (k);                                          \
            g##k = gtg4[(size_t)(b * 8 + hs * 4 + (u >> 9)) * 4096 + s * 512 +    \
                        (u & 511)];                                               \
        }
        LG(0) LG(1) LG(2) LG(3) LG(4) LG(5) LG(6) LG(7)
#undef LG
        f4v a0, a1, a2, a3, a4, a5, a6, a7;
#define LA(k2, lt, half)                                                          \
        a##k2 = *(const f4v*)&adjrow[s * 128 + (lt) * 32 + q * 8 + (half) * 4];
        LA(0, 0, 0) LA(1, 0, 1) LA(2, 1, 0) LA(3, 1, 1)
        LA(4, 2, 0) LA(5, 2, 1) LA(6, 3, 0) LA(7, 3, 1)
#undef LA
        float4 ev = make_float4(0.f, 0.f, 0.f, 0.f);
        if (t < 128) ev = ejt4[(size_t)(hs * 4 + (t >> 5)) * 256 + s * 32 + (t & 31)];
        __syncthreads();  // prior super's LDS reads done
#define SG(k)                                                                     \
        {                                                                         \
            const int u = t + 256 * (k);                                          \
            char* dstp = (char*)gts + (u >> 9) * 10240 + ((u >> 7) & 3) * 2560 +  \
                         ((u >> 2) & 31) * 80 + (u & 3) * 16;                     \
            *(float4*)dstp = g##k;                                                \
        }
        SG(0) SG(1) SG(2) SG(3) SG(4) SG(5) SG(6) SG(7)
#undef SG
        if (t < 128) *(float4*)&ejt[t >> 5][(t & 31) * 4] = ev;
        __syncthreads();  // LDS tile visible

        // ---- compute: 4 j-steps of 32, A built in named regs only
#define LT(lt, aA, aB)                                                            \
        {                                                                         \
            const f4v ej0 = *(const f4v*)&ejt[wave][(lt) * 32 + q * 8];           \
            const f4v ej1 = *(const f4v*)&ejt[wave][(lt) * 32 + q * 8 + 4];       \
            s8v A;                                                                \
            A[0] = bf16rne(aA[0] * __expf(lrelu(ei + ej0[0])));                   \
            A[1] = bf16rne(aA[1] * __expf(lrelu(ei + ej0[1])));                   \
            A[2] = bf16rne(aA[2] * __expf(lrelu(ei + ej0[2])));                   \
            A[3] = bf16rne(aA[3] * __expf(lrelu(ei + ej0[3])));                   \
            A[4] = bf16rne(aB[0] * __expf(lrelu(ei + ej1[0])));                   \
            A[5] = bf16rne(aB[1] * __expf(lrelu(ei + ej1[1])));                   \
            A[6] = bf16rne(aB[2] * __expf(lrelu(ei + ej1[2])));                   \
            A[7] = bf16rne(aB[3] * __expf(lrelu(ei + ej1[3])));                   \
            const s8v B0 = *(const s8v*)&gts[wave][lt][m][q * 8];                 \
            const s8v B1 = *(const s8v*)&gts[wave][lt][m + 16][q * 8];            \
            acc0 = __builtin_amdgcn_mfma_f32_16x16x32_bf16(A, B0, acc0, 0, 0, 0); \
            acc1 = __builtin_amdgcn_mfma_f32_16x16x32_bf16(A, B1, acc1, 0, 0, 0); \
        }
        LT(0, a0, a1) LT(1, a2, a3) LT(2, a4, a5) LT(3, a6, a7)
#undef LT
    }

    // ---- epilogue: C layout col=lane&15, row=quad*4+reg
    float* op = out + (size_t)(b * NN + i0) * 256;
#pragma unroll
    for (int r = 0; r < 4; ++r) {
        const int row = q * 4 + r;
        op[(size_t)row * 256 + h * 32 + m] = acc0[r];
        op[(size_t)row * 256 + h * 32 + 16 + m] = acc1[r];
    }
}

// ---------------------------------------------------------------------------
extern "C" void kernel_launch(void* const* d_in, const int* in_sizes, int n_in,
                              void* d_out, int out_size, void* d_ws, size_t ws_size,
                              hipStream_t stream) {
    const float* h      = (const float*)d_in[0];  // [4,1024,256]
    const float* adj    = (const float*)d_in[1];  // [4,1024,1024,1]
    const float* W      = (const float*)d_in[2];  // [256,256]
    const float* attn_w = (const float*)d_in[3];  // [64]
    float* out = (float*)d_out;                   // [4,1024,256]

    float* ws = (float*)d_ws;
    float* g    = ws;                    // 1,048,576 f
    float* e_i  = g + NROW * 256;        // 32,768 f
    float* e_j  = e_i + NROW * 8;        // 32,768 f
    float* e_jt = e_j + NROW * 8;        // 32,768 f  [b][h][n]
    float* ps   = e_jt + NROW * 8;       // 262,144 f
    short* Gt   = (short*)(ps + 8 * NROW * 8);  // 2,097,152 shorts (4MB)

    k_gemm_ei<<<NROW / 8, 256, 0, stream>>>(h, W, attn_w, g, e_i, e_j, e_jt);
    k_s<<<512, 256, 0, stream>>>(adj, e_i, e_j, ps);
    k_prep<<<256, 256, 0, stream>>>(ps, g, Gt);
    k_out_mfma<<<512, 256, 0, stream>>>(adj, Gt, e_i, e_jt, out);
}